// Round 2
// baseline (454.343 us; speedup 1.0000x reference)
//
#include <hip/hip_runtime.h>

// FernBitWord: out[n][j][h][w] = clip((I1 - I2 - th[j] + 0.5)/4, 0, 1)
// I1/I2 = bilinear taps of zero-padded (PAD=3) channel-1 of x, integer
// offsets y,x in [0,5] (per-bit uniform) + fractional weights.
//
// Round-2 design: write-BW-bound (419 MB out). Thread = 4x4 px micro-tile
// per bit (5x5 LDS patch, 3.1 reads/px vs 5) + float4 stores (16B/lane,
// same shape as the 6.2TB/s fills). LDS window is SKEWED (phys = c + c/4)
// so the 16B lane stride becomes a 5-float stride -> gcd(5,32)=1 -> no
// bank conflicts. Tile: 32 rows x 160 cols x 16 bits; 320 thr; grid 5*8*32.

#define PROWS 38             // 32 output rows + 6 halo
#define PSTR  208            // skewed floats per row (>= 166 + 166/4 = 207.. use 208)
#define GBITS 16             // bits per block
#define HT    32             // output rows per tile
#define BLK   320            // 5 waves: 40 col-groups x 8 row-groups

__device__ __forceinline__ float clamp01(float v) {
    return fminf(fmaxf(v, 0.f), 1.f);
}

__global__ __launch_bounds__(BLK) void fern_kernel(
    const float* __restrict__ x,
    const float* __restrict__ dx1, const float* __restrict__ dx2,
    const float* __restrict__ dy1, const float* __restrict__ dy2,
    const float* __restrict__ th,
    float* __restrict__ out)
{
    const int rt = blockIdx.x;   // 0..4   row tile (32 rows each)
    const int bg = blockIdx.y;   // 0..7   bit group (16 bits each)
    const int n  = blockIdx.z;   // 0..31

    __shared__ float  Wbuf[PROWS * PSTR];   // 31,616 B skewed window
    __shared__ float4 Pw[GBITS][2];         // pre-scaled bilinear weights
    __shared__ float  Pc[GBITS];            // (0.5 - th)*0.25
    __shared__ int    Po[GBITS][4];         // y1*PSTR, x1, y2*PSTR, x2
    __shared__ float  red[BLK / 64];
    __shared__ float  Lsh;

    const int tid = threadIdx.x;

    // ---- L = max |param| over all 4 M*K arrays (exact, order-free) ----
    float m = 0.f;
    if (tid < 128) {
        m = fmaxf(fmaxf(fabsf(dx1[tid]), fabsf(dx2[tid])),
                  fmaxf(fabsf(dy1[tid]), fabsf(dy2[tid])));
    }
    #pragma unroll
    for (int d = 32; d >= 1; d >>= 1) m = fmaxf(m, __shfl_xor(m, d));
    const int lane = tid & 63, wid = tid >> 6;
    if (lane == 0) red[wid] = m;
    __syncthreads();
    if (tid == 0) {
        float L = red[0];
        #pragma unroll
        for (int i = 1; i < BLK / 64; ++i) L = fmaxf(L, red[i]);
        Lsh = L;
    }
    __syncthreads();
    const float L = Lsh;
    const int shift = 3 - (int)ceilf(L);    // matches astype(int32) trunc

    // ---- per-bit params (16 bits of this group) ----
    if (tid < GBITS) {
        const int j = bg * GBITS + tid;
        const float a1 = dx1[j], a2 = dx2[j], b1 = dy1[j], b2 = dy2[j];
        const float fa1 = floorf(a1), fa2 = floorf(a2);
        const float fb1 = floorf(b1), fb2 = floorf(b2);
        int x1 = (int)(L + fa1) + shift; x1 = min(max(x1, 0), 5);
        int y1 = (int)(L + fb1) + shift; y1 = min(max(y1, 0), 5);
        int x2 = (int)(L + fa2) + shift; x2 = min(max(x2, 0), 5);
        int y2 = (int)(L + fb2) + shift; y2 = min(max(y2, 0), 5);
        const float fx1 = a1 - fa1, fy1 = b1 - fb1;
        const float fx2 = a2 - fa2, fy2 = b2 - fb2;
        // +0.25 on interp1, -0.25 on interp2 (exact pow2 scale)
        Pw[tid][0] = make_float4( 0.25f*(1.f-fx1)*(1.f-fy1),  0.25f*fx1*(1.f-fy1),
                                  0.25f*(1.f-fx1)*fy1,        0.25f*fx1*fy1);
        Pw[tid][1] = make_float4(-0.25f*(1.f-fx2)*(1.f-fy2), -0.25f*fx2*(1.f-fy2),
                                 -0.25f*(1.f-fx2)*fy2,       -0.25f*fx2*fy2);
        Pc[tid] = (0.5f - th[j]) * 0.25f;
        Po[tid][0] = y1 * PSTR;  Po[tid][1] = x1;
        Po[tid][2] = y2 * PSTR;  Po[tid][3] = x2;
    }

    // ---- stage skewed zero-padded window: 38 rows x 166 cols ----
    const float* __restrict__ src = x + ((size_t)n * 3 + 1) * 25600;
    const int h0 = rt * HT;
    for (int e = tid; e < PROWS * 166; e += BLK) {
        const int r = e / 166, c = e - r * 166;
        const int sr = h0 + r - 3, sc = c - 3;
        float v = 0.f;
        if ((unsigned)sr < 160u && (unsigned)sc < 160u) v = src[sr * 160 + sc];
        Wbuf[r * PSTR + c + (c >> 2)] = v;   // skew: stride-16B lanes -> stride-5
    }
    __syncthreads();

    // ---- compute: thread = 4 cols x 4 rows per bit ----
    const int cg = tid % 40, rg = tid / 40;
    const int w0 = cg * 4, rbase = rg * 4;
    const int rowoff = rbase * PSTR;

    float* __restrict__ outp =
        out + ((size_t)n * 128 + bg * GBITS) * 25600 + (h0 + rbase) * 160 + w0;

    #pragma unroll 1
    for (int j = 0; j < GBITS; ++j) {
        const float4 s1 = Pw[j][0];
        const float4 s2 = Pw[j][1];
        const float  c0 = Pc[j];

        float acc[4][4];
        #pragma unroll
        for (int i = 0; i < 4; ++i)
            #pragma unroll
            for (int k = 0; k < 4; ++k) acc[i][k] = c0;

        float P[5][5];
        int pc[5];

        // ---- interp 1 ----
        {
            const int o  = Po[j][0] + rowoff;
            const int cx = Po[j][1] + w0;
            #pragma unroll
            for (int c = 0; c < 5; ++c) { int q = cx + c; pc[c] = q + (q >> 2); }
            #pragma unroll
            for (int i = 0; i < 5; ++i)
                #pragma unroll
                for (int c = 0; c < 5; ++c)
                    P[i][c] = Wbuf[o + i * PSTR + pc[c]];
            #pragma unroll
            for (int i = 0; i < 4; ++i)
                #pragma unroll
                for (int k = 0; k < 4; ++k)
                    acc[i][k] += s1.x*P[i][k] + s1.y*P[i][k+1]
                               + s1.z*P[i+1][k] + s1.w*P[i+1][k+1];
        }
        // ---- interp 2 (negative weights) ----
        {
            const int o  = Po[j][2] + rowoff;
            const int cx = Po[j][3] + w0;
            #pragma unroll
            for (int c = 0; c < 5; ++c) { int q = cx + c; pc[c] = q + (q >> 2); }
            #pragma unroll
            for (int i = 0; i < 5; ++i)
                #pragma unroll
                for (int c = 0; c < 5; ++c)
                    P[i][c] = Wbuf[o + i * PSTR + pc[c]];
            #pragma unroll
            for (int i = 0; i < 4; ++i)
                #pragma unroll
                for (int k = 0; k < 4; ++k)
                    acc[i][k] += s2.x*P[i][k] + s2.y*P[i][k+1]
                               + s2.z*P[i+1][k] + s2.w*P[i+1][k+1];
        }

        // ---- clamp + float4 stores (16B/lane, rows rbase..rbase+3) ----
        #pragma unroll
        for (int i = 0; i < 4; ++i) {
            float4 v;
            v.x = clamp01(acc[i][0]); v.y = clamp01(acc[i][1]);
            v.z = clamp01(acc[i][2]); v.w = clamp01(acc[i][3]);
            *reinterpret_cast<float4*>(outp + i * 160) = v;
        }
        outp += 25600;
    }
}

extern "C" void kernel_launch(void* const* d_in, const int* in_sizes, int n_in,
                              void* d_out, int out_size, void* d_ws, size_t ws_size,
                              hipStream_t stream) {
    const float* x   = (const float*)d_in[0];
    const float* dx1 = (const float*)d_in[1];
    const float* dx2 = (const float*)d_in[2];
    const float* dy1 = (const float*)d_in[3];
    const float* dy2 = (const float*)d_in[4];
    const float* th  = (const float*)d_in[5];
    float* out = (float*)d_out;

    dim3 grid(5, 8, 32);   // row-tiles x bit-groups x N
    fern_kernel<<<grid, BLK, 0, stream>>>(x, dx1, dx2, dy1, dy2, th, out);
}